// Round 14
// baseline (30.157 us; speedup 1.0000x reference)
//
#include <hip/hip_runtime.h>
#include <hip/hip_bf16.h>
#include <cstdint>

// VQ-VAE vector quantize: N=65536 vectors, D=64, K=512 codes.
// d_in[0]: inputs fp32 [65536,64], d_in[1]: embeddings fp32 [512,64]
// d_out: [0]=loss, [1..4194304]=latent (gathered fp32 embeddings)
//
// R14: R11 structure (best: 24.25us) minus the loss kernel. vq_setup zeroes
// out[0]; each main block contributes its scaled loss partial with ONE plain
// device-scope atomicAdd (no release/acquire fences - R8's poison was the
// explicit memory-ordering, not atomics). 2 kernels total.

typedef __attribute__((ext_vector_type(8))) short bf16x8;
typedef __attribute__((ext_vector_type(4))) float f32x4;

__device__ __forceinline__ short f2bf(float f) {
    uint32_t u = __builtin_bit_cast(uint32_t, f);
    u += 0x7FFFu + ((u >> 16) & 1u);   // round-to-nearest-even
    return (short)(u >> 16);
}

// ws layout (bytes):
//  [0, 65536)     : B fragments bf16(-e), [ct(32)][ks(2)][lane(64)] x 16B
//  [65536, 67584) : ee_t[512] fp32 = 0.5*||e_k||^2, TRANSPOSED [cb(16)][ct(32)]
#define WS_EE   65536

// ---------------- Kernel 1: setup (16 blocks x 256) ----------------
__global__ __launch_bounds__(256)
void vq_setup(const float* __restrict__ emb, char* __restrict__ ws,
              float* __restrict__ out) {
    const int tid = threadIdx.x, bid = blockIdx.x;
    bf16x8* bfrag = (bf16x8*)ws;
    float* eet = (float*)(ws + WS_EE);
    if (bid == 0 && tid == 0) out[0] = 0.f;   // loss accumulator init

    const int s = bid * 256 + tid;
    const int ct = s >> 7, ks = (s >> 6) & 1, ln = s & 63;
    const int code = (ct << 4) | (ln & 15);
    const int d0 = ks * 32 + ((ln >> 4) << 3);
    const float* src = emb + code * 64 + d0;
    float4 v0 = *(const float4*)src;
    float4 v1 = *(const float4*)(src + 4);
    bf16x8 b;
    b[0] = f2bf(-v0.x); b[1] = f2bf(-v0.y); b[2] = f2bf(-v0.z); b[3] = f2bf(-v0.w);
    b[4] = f2bf(-v1.x); b[5] = f2bf(-v1.y); b[6] = f2bf(-v1.z); b[7] = f2bf(-v1.w);
    bfrag[s] = b;

    if (tid < 32) {
        const int c = bid * 32 + tid;
        const float4* e4 = (const float4*)(emb + c * 64);
        float acc = 0.f;
        #pragma unroll
        for (int q = 0; q < 16; ++q) {
            float4 v = e4[q];
            acc = fmaf(v.x, v.x, fmaf(v.y, v.y, fmaf(v.z, v.z, fmaf(v.w, v.w, acc))));
        }
        eet[(c & 15) * 32 + (c >> 4)] = 0.5f * acc;   // transposed, pre-halved
    }
}

// ---------------- Kernel 2: main (1024 blocks x 256) ----------------
// Block owns 64 rows. Wave w holds codes [w*128, w*128+128) in VGPRs and
// computes its partial argmin for ALL 64 rows; combine across waves in LDS.
__global__ __launch_bounds__(256)
void vq_main(const float* __restrict__ flat, const float* __restrict__ emb,
             char* __restrict__ ws, float* __restrict__ out) {
    __shared__ bf16x8 albuf[4][2][64];   // 4 KB  [rt][ks][lane] A fragments
    __shared__ float  cmb[4][64];        // 1 KB  [wave][row] packed partial min
    __shared__ float  red[4];

    const int tid = threadIdx.x, bid = blockIdx.x;
    const int lane = tid & 63, wid = tid >> 6;
    const int cb = lane & 15, g = lane >> 4;
    const int rb = bid * 64;             // block's 64 rows
    const char* wsg = (const char*)ws;

    // ---- A loads: wave stages its OWN 16 rows (row-tile wid) ----
    const float* asrc = flat + (long)(rb + wid * 16 + cb) * 64 + (g << 3);
    float4 ar00 = *(const float4*)asrc;
    float4 ar01 = *(const float4*)(asrc + 4);
    float4 ar10 = *(const float4*)(asrc + 32);
    float4 ar11 = *(const float4*)(asrc + 36);

    // ---- B slice: wave's 8 col-tiles (128 codes) -> 64 VGPRs, loaded once ----
    const bf16x8* wsb = (const bf16x8*)wsg;
    bf16x8 bv[8][2];
    #pragma unroll
    for (int c = 0; c < 8; ++c) {
        bv[c][0] = wsb[(wid * 8 + c) * 128 + lane];
        bv[c][1] = wsb[(wid * 8 + c) * 128 + 64 + lane];
    }

    // ---- half-norms for this wave's 8 col-tiles, this lane's col class ----
    float hvv[8];
    {
        const float4* hp = (const float4*)(wsg + WS_EE + cb * 128 + wid * 32);
        float4 h0 = hp[0], h1 = hp[1];
        hvv[0] = h0.x; hvv[1] = h0.y; hvv[2] = h0.z; hvv[3] = h0.w;
        hvv[4] = h1.x; hvv[5] = h1.y; hvv[6] = h1.z; hvv[7] = h1.w;
    }

    // ---- ||x||^2 partial (wave's own rows only; disjoint across waves) ----
    float xx = 0.f;
    {
        float4 v;
        v = ar00; xx = fmaf(v.x, v.x, fmaf(v.y, v.y, fmaf(v.z, v.z, fmaf(v.w, v.w, xx))));
        v = ar01; xx = fmaf(v.x, v.x, fmaf(v.y, v.y, fmaf(v.z, v.z, fmaf(v.w, v.w, xx))));
        v = ar10; xx = fmaf(v.x, v.x, fmaf(v.y, v.y, fmaf(v.z, v.z, fmaf(v.w, v.w, xx))));
        v = ar11; xx = fmaf(v.x, v.x, fmaf(v.y, v.y, fmaf(v.z, v.z, fmaf(v.w, v.w, xx))));
    }

    // ---- convert own A rows to bf16 fragments and share via LDS ----
    {
        bf16x8 f;
        f[0] = f2bf(ar00.x); f[1] = f2bf(ar00.y); f[2] = f2bf(ar00.z); f[3] = f2bf(ar00.w);
        f[4] = f2bf(ar01.x); f[5] = f2bf(ar01.y); f[6] = f2bf(ar01.z); f[7] = f2bf(ar01.w);
        albuf[wid][0][lane] = f;
        f[0] = f2bf(ar10.x); f[1] = f2bf(ar10.y); f[2] = f2bf(ar10.z); f[3] = f2bf(ar10.w);
        f[4] = f2bf(ar11.x); f[5] = f2bf(ar11.y); f[6] = f2bf(ar11.z); f[7] = f2bf(ar11.w);
        albuf[wid][1][lane] = f;
    }
    __syncthreads();

    // ---- main loop: 4 row-tiles x 8 col-tiles, B from VGPRs ----
    float pm[4][4];
    #pragma unroll
    for (int rt = 0; rt < 4; ++rt)
        #pragma unroll
        for (int j = 0; j < 4; ++j) pm[rt][j] = __builtin_bit_cast(float, 0x7F800000u);

    #pragma unroll
    for (int rt = 0; rt < 4; ++rt) {
        bf16x8 a0 = albuf[rt][0][lane];
        bf16x8 a1 = albuf[rt][1][lane];
        #pragma unroll
        for (int c = 0; c < 8; ++c) {
            const float h = hvv[c];
            const int colv = ((wid * 8 + c) << 4) | cb;
            f32x4 acc = {h, h, h, h};        // 0.5||e||^2 - x.e   (B = -e)
            acc = __builtin_amdgcn_mfma_f32_16x16x32_bf16(a0, bv[c][0], acc, 0, 0, 0);
            acc = __builtin_amdgcn_mfma_f32_16x16x32_bf16(a1, bv[c][1], acc, 0, 0, 0);
            #pragma unroll
            for (int j = 0; j < 4; ++j) {
                uint32_t dp = (__builtin_bit_cast(uint32_t, acc[j]) & 0xFFFFFE00u) | (uint32_t)colv;
                pm[rt][j] = fminf(pm[rt][j], __builtin_bit_cast(float, dp));
            }
        }
    }

    // ---- butterfly min over the 16 column-class lanes (per row-tile) ----
    #pragma unroll
    for (int m = 1; m < 16; m <<= 1) {
        #pragma unroll
        for (int rt = 0; rt < 4; ++rt)
            #pragma unroll
            for (int j = 0; j < 4; ++j)
                pm[rt][j] = fminf(pm[rt][j], __shfl_xor(pm[rt][j], m, 64));
    }
    // group g now holds this wave's partial winner for rows rt*16 + g*4 + j
    if (cb == 0) {
        #pragma unroll
        for (int rt = 0; rt < 4; ++rt)
            #pragma unroll
            for (int j = 0; j < 4; ++j)
                cmb[wid][rt * 16 + g * 4 + j] = pm[rt][j];
    }
    __syncthreads();

    // ---- epilogue: cross-wave combine + gather + store + loss ----
    // thread t: row = t>>2 (0..63), seg = t&3 (16 floats each)
    const int row = tid >> 2, seg = tid & 3;
    const float mn = fminf(fminf(cmb[0][row], cmb[1][row]),
                           fminf(cmb[2][row], cmb[3][row]));
    const uint32_t mbits = __builtin_bit_cast(uint32_t, mn);
    const int ix = (int)(mbits & 0x1FFu);

    const float4* esrc = (const float4*)(emb + ix * 64 + seg * 16);
    float4 e0 = esrc[0], e1 = esrc[1], e2 = esrc[2], e3 = esrc[3];
    float* ob = out + 1 + (long)(rb + row) * 64 + seg * 16;
    ob[0]  = e0.x; ob[1]  = e0.y; ob[2]  = e0.z; ob[3]  = e0.w;
    ob[4]  = e1.x; ob[5]  = e1.y; ob[6]  = e1.z; ob[7]  = e1.w;
    ob[8]  = e2.x; ob[9]  = e2.y; ob[10] = e2.z; ob[11] = e2.w;
    ob[12] = e3.x; ob[13] = e3.y; ob[14] = e3.z; ob[15] = e3.w;

    // loss partial: xx (per-lane, disjoint rows) + 2*unpack(min) once per row
    float t = xx;
    if (seg == 0) {
        float v = __builtin_bit_cast(float, mbits & 0xFFFFFE00u);
        t = fmaf(2.f, v, t);
    }
    #pragma unroll
    for (int m = 32; m; m >>= 1) t += __shfl_down(t, m, 64);
    if (lane == 0) red[wid] = t;
    __syncthreads();

    // ---- ONE plain device-scope atomicAdd per block (no fences) ----
    // loss = 0.25*e_loss + q_loss = 1.25 * mse (forward)
    if (tid == 0) {
        float s = red[0] + red[1] + red[2] + red[3];
        atomicAdd(out, 1.25f * s / 4194304.0f);
    }
}

extern "C" void kernel_launch(void* const* d_in, const int* in_sizes, int n_in,
                              void* d_out, int out_size, void* d_ws, size_t ws_size,
                              hipStream_t stream) {
    const float* flat = (const float*)d_in[0];   // [65536,64]
    const float* emb  = (const float*)d_in[1];   // [512,64]
    float* out = (float*)d_out;
    char* ws = (char*)d_ws;

    vq_setup<<<16, 256, 0, stream>>>(emb, ws, out);
    vq_main<<<1024, 256, 0, stream>>>(flat, emb, ws, out);
}

// Round 15
// 24.177 us; speedup vs baseline: 1.2474x; 1.2474x over previous
//
#include <hip/hip_runtime.h>
#include <hip/hip_bf16.h>
#include <cstdint>

// VQ-VAE vector quantize: N=65536 vectors, D=64, K=512 codes.
// d_in[0]: inputs fp32 [65536,64], d_in[1]: embeddings fp32 [512,64]
// d_out: [0]=loss, [1..4194304]=latent (gathered fp32 embeddings)
//
// R15 = R11 verbatim (measured best: 24.25 us). Codebook-in-VGPRs: each wave
// holds a 128-code slice in 64 VGPRs (loaded once from the precomputed
// fragment-ordered ws), loops over 4 row-tiles staged in 4 KB LDS.
// Cross-wave argmin combine via LDS; NO cross-block atomics of any kind
// (R8: fenced atomics +54us; R14: plain atomicAdd +6us via out[0] cache-line
// ping-pong with latent stores). 3-kernel chain is the cheapest combine.

typedef __attribute__((ext_vector_type(8))) short bf16x8;
typedef __attribute__((ext_vector_type(4))) float f32x4;

__device__ __forceinline__ short f2bf(float f) {
    uint32_t u = __builtin_bit_cast(uint32_t, f);
    u += 0x7FFFu + ((u >> 16) & 1u);   // round-to-nearest-even
    return (short)(u >> 16);
}

// ws layout (bytes):
//  [0, 65536)     : B fragments bf16(-e), [ct(32)][ks(2)][lane(64)] x 16B
//  [65536, 67584) : ee_t[512] fp32 = 0.5*||e_k||^2, TRANSPOSED [cb(16)][ct(32)]
//  [67584, 71680) : partials[1024] fp32
#define WS_EE   65536
#define WS_PART 67584

// ---------------- Kernel 1: setup (16 blocks x 256) ----------------
__global__ __launch_bounds__(256)
void vq_setup(const float* __restrict__ emb, char* __restrict__ ws) {
    const int tid = threadIdx.x, bid = blockIdx.x;
    bf16x8* bfrag = (bf16x8*)ws;
    float* eet = (float*)(ws + WS_EE);

    const int s = bid * 256 + tid;
    const int ct = s >> 7, ks = (s >> 6) & 1, ln = s & 63;
    const int code = (ct << 4) | (ln & 15);
    const int d0 = ks * 32 + ((ln >> 4) << 3);
    const float* src = emb + code * 64 + d0;
    float4 v0 = *(const float4*)src;
    float4 v1 = *(const float4*)(src + 4);
    bf16x8 b;
    b[0] = f2bf(-v0.x); b[1] = f2bf(-v0.y); b[2] = f2bf(-v0.z); b[3] = f2bf(-v0.w);
    b[4] = f2bf(-v1.x); b[5] = f2bf(-v1.y); b[6] = f2bf(-v1.z); b[7] = f2bf(-v1.w);
    bfrag[s] = b;

    if (tid < 32) {
        const int c = bid * 32 + tid;
        const float4* e4 = (const float4*)(emb + c * 64);
        float acc = 0.f;
        #pragma unroll
        for (int q = 0; q < 16; ++q) {
            float4 v = e4[q];
            acc = fmaf(v.x, v.x, fmaf(v.y, v.y, fmaf(v.z, v.z, fmaf(v.w, v.w, acc))));
        }
        eet[(c & 15) * 32 + (c >> 4)] = 0.5f * acc;   // transposed, pre-halved
    }
}

// ---------------- Kernel 2: main (1024 blocks x 256) ----------------
// Block owns 64 rows. Wave w holds codes [w*128, w*128+128) in VGPRs and
// computes its partial argmin for ALL 64 rows; combine across waves in LDS.
__global__ __launch_bounds__(256)
void vq_main(const float* __restrict__ flat, const float* __restrict__ emb,
             char* __restrict__ ws, float* __restrict__ out) {
    __shared__ bf16x8 albuf[4][2][64];   // 4 KB  [rt][ks][lane] A fragments
    __shared__ float  cmb[4][64];        // 1 KB  [wave][row] packed partial min
    __shared__ float  red[4];

    const int tid = threadIdx.x, bid = blockIdx.x;
    const int lane = tid & 63, wid = tid >> 6;
    const int cb = lane & 15, g = lane >> 4;
    const int rb = bid * 64;             // block's 64 rows
    const char* wsg = (const char*)ws;

    // ---- A loads: wave stages its OWN 16 rows (row-tile wid) ----
    const float* asrc = flat + (long)(rb + wid * 16 + cb) * 64 + (g << 3);
    float4 ar00 = *(const float4*)asrc;
    float4 ar01 = *(const float4*)(asrc + 4);
    float4 ar10 = *(const float4*)(asrc + 32);
    float4 ar11 = *(const float4*)(asrc + 36);

    // ---- B slice: wave's 8 col-tiles (128 codes) -> 64 VGPRs, loaded once ----
    const bf16x8* wsb = (const bf16x8*)wsg;
    bf16x8 bv[8][2];
    #pragma unroll
    for (int c = 0; c < 8; ++c) {
        bv[c][0] = wsb[(wid * 8 + c) * 128 + lane];
        bv[c][1] = wsb[(wid * 8 + c) * 128 + 64 + lane];
    }

    // ---- half-norms for this wave's 8 col-tiles, this lane's col class ----
    float hvv[8];
    {
        const float4* hp = (const float4*)(wsg + WS_EE + cb * 128 + wid * 32);
        float4 h0 = hp[0], h1 = hp[1];
        hvv[0] = h0.x; hvv[1] = h0.y; hvv[2] = h0.z; hvv[3] = h0.w;
        hvv[4] = h1.x; hvv[5] = h1.y; hvv[6] = h1.z; hvv[7] = h1.w;
    }

    // ---- ||x||^2 partial (wave's own rows only; disjoint across waves) ----
    float xx = 0.f;
    {
        float4 v;
        v = ar00; xx = fmaf(v.x, v.x, fmaf(v.y, v.y, fmaf(v.z, v.z, fmaf(v.w, v.w, xx))));
        v = ar01; xx = fmaf(v.x, v.x, fmaf(v.y, v.y, fmaf(v.z, v.z, fmaf(v.w, v.w, xx))));
        v = ar10; xx = fmaf(v.x, v.x, fmaf(v.y, v.y, fmaf(v.z, v.z, fmaf(v.w, v.w, xx))));
        v = ar11; xx = fmaf(v.x, v.x, fmaf(v.y, v.y, fmaf(v.z, v.z, fmaf(v.w, v.w, xx))));
    }

    // ---- convert own A rows to bf16 fragments and share via LDS ----
    {
        bf16x8 f;
        f[0] = f2bf(ar00.x); f[1] = f2bf(ar00.y); f[2] = f2bf(ar00.z); f[3] = f2bf(ar00.w);
        f[4] = f2bf(ar01.x); f[5] = f2bf(ar01.y); f[6] = f2bf(ar01.z); f[7] = f2bf(ar01.w);
        albuf[wid][0][lane] = f;
        f[0] = f2bf(ar10.x); f[1] = f2bf(ar10.y); f[2] = f2bf(ar10.z); f[3] = f2bf(ar10.w);
        f[4] = f2bf(ar11.x); f[5] = f2bf(ar11.y); f[6] = f2bf(ar11.z); f[7] = f2bf(ar11.w);
        albuf[wid][1][lane] = f;
    }
    __syncthreads();

    // ---- main loop: 4 row-tiles x 8 col-tiles, B from VGPRs ----
    float pm[4][4];
    #pragma unroll
    for (int rt = 0; rt < 4; ++rt)
        #pragma unroll
        for (int j = 0; j < 4; ++j) pm[rt][j] = __builtin_bit_cast(float, 0x7F800000u);

    #pragma unroll
    for (int rt = 0; rt < 4; ++rt) {
        bf16x8 a0 = albuf[rt][0][lane];
        bf16x8 a1 = albuf[rt][1][lane];
        #pragma unroll
        for (int c = 0; c < 8; ++c) {
            const float h = hvv[c];
            const int colv = ((wid * 8 + c) << 4) | cb;
            f32x4 acc = {h, h, h, h};        // 0.5||e||^2 - x.e   (B = -e)
            acc = __builtin_amdgcn_mfma_f32_16x16x32_bf16(a0, bv[c][0], acc, 0, 0, 0);
            acc = __builtin_amdgcn_mfma_f32_16x16x32_bf16(a1, bv[c][1], acc, 0, 0, 0);
            #pragma unroll
            for (int j = 0; j < 4; ++j) {
                uint32_t dp = (__builtin_bit_cast(uint32_t, acc[j]) & 0xFFFFFE00u) | (uint32_t)colv;
                pm[rt][j] = fminf(pm[rt][j], __builtin_bit_cast(float, dp));
            }
        }
    }

    // ---- butterfly min over the 16 column-class lanes (per row-tile) ----
    #pragma unroll
    for (int m = 1; m < 16; m <<= 1) {
        #pragma unroll
        for (int rt = 0; rt < 4; ++rt)
            #pragma unroll
            for (int j = 0; j < 4; ++j)
                pm[rt][j] = fminf(pm[rt][j], __shfl_xor(pm[rt][j], m, 64));
    }
    // group g now holds this wave's partial winner for rows rt*16 + g*4 + j
    if (cb == 0) {
        #pragma unroll
        for (int rt = 0; rt < 4; ++rt)
            #pragma unroll
            for (int j = 0; j < 4; ++j)
                cmb[wid][rt * 16 + g * 4 + j] = pm[rt][j];
    }
    __syncthreads();

    // ---- epilogue: cross-wave combine + gather + store + loss ----
    // thread t: row = t>>2 (0..63), seg = t&3 (16 floats each)
    const int row = tid >> 2, seg = tid & 3;
    const float mn = fminf(fminf(cmb[0][row], cmb[1][row]),
                           fminf(cmb[2][row], cmb[3][row]));
    const uint32_t mbits = __builtin_bit_cast(uint32_t, mn);
    const int ix = (int)(mbits & 0x1FFu);

    const float4* esrc = (const float4*)(emb + ix * 64 + seg * 16);
    float4 e0 = esrc[0], e1 = esrc[1], e2 = esrc[2], e3 = esrc[3];
    float* ob = out + 1 + (long)(rb + row) * 64 + seg * 16;
    ob[0]  = e0.x; ob[1]  = e0.y; ob[2]  = e0.z; ob[3]  = e0.w;
    ob[4]  = e1.x; ob[5]  = e1.y; ob[6]  = e1.z; ob[7]  = e1.w;
    ob[8]  = e2.x; ob[9]  = e2.y; ob[10] = e2.z; ob[11] = e2.w;
    ob[12] = e3.x; ob[13] = e3.y; ob[14] = e3.z; ob[15] = e3.w;

    // loss partial: xx (per-lane, disjoint rows) + 2*unpack(min) once per row
    float t = xx;
    if (seg == 0) {
        float v = __builtin_bit_cast(float, mbits & 0xFFFFFE00u);
        t = fmaf(2.f, v, t);
    }
    #pragma unroll
    for (int m = 32; m; m >>= 1) t += __shfl_down(t, m, 64);
    if (lane == 0) red[wid] = t;
    __syncthreads();
    if (tid == 0) {
        float* part = (float*)(ws + WS_PART);
        part[bid] = red[0] + red[1] + red[2] + red[3];
    }
}

// ---------------- Kernel 3: deterministic final reduce (1 block) ----------------
__global__ __launch_bounds__(256)
void vq_loss(const float* __restrict__ partials, float* __restrict__ out) {
    __shared__ float red[4];
    const int tid = threadIdx.x;
    float acc = partials[tid] + partials[tid + 256] + partials[tid + 512] + partials[tid + 768];
    #pragma unroll
    for (int m = 32; m; m >>= 1) acc += __shfl_down(acc, m, 64);
    if ((tid & 63) == 0) red[tid >> 6] = acc;
    __syncthreads();
    // loss = 0.25*e_loss + q_loss = 1.25 * mse (forward)
    if (tid == 0) out[0] = 1.25f * (red[0] + red[1] + red[2] + red[3]) / 4194304.0f;
}

extern "C" void kernel_launch(void* const* d_in, const int* in_sizes, int n_in,
                              void* d_out, int out_size, void* d_ws, size_t ws_size,
                              hipStream_t stream) {
    const float* flat = (const float*)d_in[0];   // [65536,64]
    const float* emb  = (const float*)d_in[1];   // [512,64]
    float* out = (float*)d_out;
    char* ws = (char*)d_ws;

    vq_setup<<<16, 256, 0, stream>>>(emb, ws);
    vq_main<<<1024, 256, 0, stream>>>(flat, emb, ws, out);
    vq_loss<<<1, 256, 0, stream>>>((const float*)(ws + WS_PART), out);
}

// Round 16
// 23.307 us; speedup vs baseline: 1.2939x; 1.0373x over previous
//
#include <hip/hip_runtime.h>
#include <hip/hip_bf16.h>
#include <cstdint>

// VQ-VAE vector quantize: N=65536 vectors, D=64, K=512 codes.
// d_in[0]: inputs fp32 [65536,64], d_in[1]: embeddings fp32 [512,64]
// d_out: [0]=loss, [1..4194304]=latent (gathered fp32 embeddings)
//
// R16: R11 (24.2us) x 2-iteration grid-stride. 512 blocks x 256 threads;
// wave keeps its 128-code B-slice in VGPRs (one load), processes 128 rows
// in 2 iters of 64; iter-1 A-loads issued under iter-0 compute (prefetch).
// albuf+cmb double-buffered; 3 barriers/block. No cross-block comms.

typedef __attribute__((ext_vector_type(8))) short bf16x8;
typedef __attribute__((ext_vector_type(4))) float f32x4;

__device__ __forceinline__ short f2bf(float f) {
    uint32_t u = __builtin_bit_cast(uint32_t, f);
    u += 0x7FFFu + ((u >> 16) & 1u);   // round-to-nearest-even
    return (short)(u >> 16);
}

__device__ __forceinline__ float sumsq4(float4 v, float acc) {
    return fmaf(v.x, v.x, fmaf(v.y, v.y, fmaf(v.z, v.z, fmaf(v.w, v.w, acc))));
}

__device__ __forceinline__ bf16x8 packpos(float4 a, float4 b) {
    bf16x8 f;
    f[0] = f2bf(a.x); f[1] = f2bf(a.y); f[2] = f2bf(a.z); f[3] = f2bf(a.w);
    f[4] = f2bf(b.x); f[5] = f2bf(b.y); f[6] = f2bf(b.z); f[7] = f2bf(b.w);
    return f;
}

// ws layout (bytes):
//  [0, 65536)     : B fragments bf16(-e), [ct(32)][ks(2)][lane(64)] x 16B
//  [65536, 67584) : ee_t[512] fp32 = 0.5*||e_k||^2, TRANSPOSED [cb(16)][ct(32)]
//  [67584, 69632) : partials[512] fp32
#define WS_EE   65536
#define WS_PART 67584

// ---------------- Kernel 1: setup (16 blocks x 256) ----------------
__global__ __launch_bounds__(256)
void vq_setup(const float* __restrict__ emb, char* __restrict__ ws) {
    const int tid = threadIdx.x, bid = blockIdx.x;
    bf16x8* bfrag = (bf16x8*)ws;
    float* eet = (float*)(ws + WS_EE);

    const int s = bid * 256 + tid;
    const int ct = s >> 7, ks = (s >> 6) & 1, ln = s & 63;
    const int code = (ct << 4) | (ln & 15);
    const int d0 = ks * 32 + ((ln >> 4) << 3);
    const float* src = emb + code * 64 + d0;
    float4 v0 = *(const float4*)src;
    float4 v1 = *(const float4*)(src + 4);
    bf16x8 b;
    b[0] = f2bf(-v0.x); b[1] = f2bf(-v0.y); b[2] = f2bf(-v0.z); b[3] = f2bf(-v0.w);
    b[4] = f2bf(-v1.x); b[5] = f2bf(-v1.y); b[6] = f2bf(-v1.z); b[7] = f2bf(-v1.w);
    bfrag[s] = b;

    if (tid < 32) {
        const int c = bid * 32 + tid;
        const float4* e4 = (const float4*)(emb + c * 64);
        float acc = 0.f;
        #pragma unroll
        for (int q = 0; q < 16; ++q) {
            float4 v = e4[q];
            acc = fmaf(v.x, v.x, fmaf(v.y, v.y, fmaf(v.z, v.z, fmaf(v.w, v.w, acc))));
        }
        eet[(c & 15) * 32 + (c >> 4)] = 0.5f * acc;   // transposed, pre-halved
    }
}

// ---------------- Kernel 2: main (512 blocks x 256) ----------------
// Block owns 128 rows (2 iters x 64). Wave w holds codes [w*128,(w+1)*128)
// in VGPRs; per iter computes partial argmin for all 64 rows; LDS combine.
__global__ __launch_bounds__(256)
void vq_main(const float* __restrict__ flat, const float* __restrict__ emb,
             char* __restrict__ ws, float* __restrict__ out) {
    __shared__ bf16x8 albuf[2][4][2][64];   // 8 KB  [buf][rt][ks][lane]
    __shared__ float  cmb[2][4][64];        // 2 KB  [buf][wave][row]
    __shared__ float  red[4];

    const int tid = threadIdx.x, bid = blockIdx.x;
    const int lane = tid & 63, wid = tid >> 6;
    const int cb = lane & 15, g = lane >> 4;
    const int rb = bid * 128;            // block's 128 rows
    const char* wsg = (const char*)ws;

    // ---- A iter-0 loads: wave's own 16 rows ----
    const float* a0src = flat + (long)(rb + wid * 16 + cb) * 64 + (g << 3);
    float4 ar00 = *(const float4*)a0src;
    float4 ar01 = *(const float4*)(a0src + 4);
    float4 ar10 = *(const float4*)(a0src + 32);
    float4 ar11 = *(const float4*)(a0src + 36);

    // ---- B slice: wave's 8 col-tiles -> 64 VGPRs, loaded once ----
    const bf16x8* wsb = (const bf16x8*)wsg;
    bf16x8 bv[8][2];
    #pragma unroll
    for (int c = 0; c < 8; ++c) {
        bv[c][0] = wsb[(wid * 8 + c) * 128 + lane];
        bv[c][1] = wsb[(wid * 8 + c) * 128 + 64 + lane];
    }

    // ---- half-norms for this wave's 8 col-tiles, this lane's col class ----
    float hvv[8];
    {
        const float4* hp = (const float4*)(wsg + WS_EE + cb * 128 + wid * 32);
        float4 h0 = hp[0], h1 = hp[1];
        hvv[0] = h0.x; hvv[1] = h0.y; hvv[2] = h0.z; hvv[3] = h0.w;
        hvv[4] = h1.x; hvv[5] = h1.y; hvv[6] = h1.z; hvv[7] = h1.w;
    }

    // ---- iter-0: ||x||^2 + convert + stage albuf[0] ----
    float xx = 0.f;
    xx = sumsq4(ar00, xx); xx = sumsq4(ar01, xx);
    xx = sumsq4(ar10, xx); xx = sumsq4(ar11, xx);
    albuf[0][wid][0][lane] = packpos(ar00, ar01);
    albuf[0][wid][1][lane] = packpos(ar10, ar11);
    __syncthreads();

    float dacc = 0.f;   // sum of winning dist' for my epilogue rows

    #pragma unroll
    for (int it = 0; it < 2; ++it) {
        // prefetch iter-1 A while computing iter-0 (loads issue now,
        // s_waitcnt deferred to first use after the MFMA block)
        float4 br00, br01, br10, br11;
        if (it == 0) {
            const float* a1src = flat + (long)(rb + 64 + wid * 16 + cb) * 64 + (g << 3);
            br00 = *(const float4*)a1src;
            br01 = *(const float4*)(a1src + 4);
            br10 = *(const float4*)(a1src + 32);
            br11 = *(const float4*)(a1src + 36);
        }

        // ---- compute: 4 row-tiles x 8 col-tiles, B from VGPRs ----
        float pm[4][4];
        #pragma unroll
        for (int rt = 0; rt < 4; ++rt)
            #pragma unroll
            for (int j = 0; j < 4; ++j) pm[rt][j] = __builtin_bit_cast(float, 0x7F800000u);

        #pragma unroll
        for (int rt = 0; rt < 4; ++rt) {
            bf16x8 a0 = albuf[it][rt][0][lane];
            bf16x8 a1 = albuf[it][rt][1][lane];
            #pragma unroll
            for (int c = 0; c < 8; ++c) {
                const float h = hvv[c];
                const int colv = ((wid * 8 + c) << 4) | cb;
                f32x4 acc = {h, h, h, h};    // 0.5||e||^2 - x.e   (B = -e)
                acc = __builtin_amdgcn_mfma_f32_16x16x32_bf16(a0, bv[c][0], acc, 0, 0, 0);
                acc = __builtin_amdgcn_mfma_f32_16x16x32_bf16(a1, bv[c][1], acc, 0, 0, 0);
                #pragma unroll
                for (int j = 0; j < 4; ++j) {
                    uint32_t dp = (__builtin_bit_cast(uint32_t, acc[j]) & 0xFFFFFE00u) | (uint32_t)colv;
                    pm[rt][j] = fminf(pm[rt][j], __builtin_bit_cast(float, dp));
                }
            }
        }

        // ---- butterfly min over the 16 column-class lanes ----
        #pragma unroll
        for (int m = 1; m < 16; m <<= 1) {
            #pragma unroll
            for (int rt = 0; rt < 4; ++rt)
                #pragma unroll
                for (int j = 0; j < 4; ++j)
                    pm[rt][j] = fminf(pm[rt][j], __shfl_xor(pm[rt][j], m, 64));
        }
        if (cb == 0) {
            #pragma unroll
            for (int rt = 0; rt < 4; ++rt)
                #pragma unroll
                for (int j = 0; j < 4; ++j)
                    cmb[it][wid][rt * 16 + g * 4 + j] = pm[rt][j];
        }

        // ---- stage iter-1 A fragments while cmb settles ----
        if (it == 0) {
            xx = sumsq4(br00, xx); xx = sumsq4(br01, xx);
            xx = sumsq4(br10, xx); xx = sumsq4(br11, xx);
            albuf[1][wid][0][lane] = packpos(br00, br01);
            albuf[1][wid][1][lane] = packpos(br10, br11);
        }
        __syncthreads();   // cmb[it] + albuf[1] visible to all waves

        // ---- epilogue for this iter's 64 rows ----
        const int row = tid >> 2, seg = tid & 3;
        const float mn = fminf(fminf(cmb[it][0][row], cmb[it][1][row]),
                               fminf(cmb[it][2][row], cmb[it][3][row]));
        const uint32_t mbits = __builtin_bit_cast(uint32_t, mn);
        const int ix = (int)(mbits & 0x1FFu);

        const float4* esrc = (const float4*)(emb + ix * 64 + seg * 16);
        float4 e0 = esrc[0], e1 = esrc[1], e2 = esrc[2], e3 = esrc[3];
        float* ob = out + 1 + (long)(rb + it * 64 + row) * 64 + seg * 16;
        ob[0]  = e0.x; ob[1]  = e0.y; ob[2]  = e0.z; ob[3]  = e0.w;
        ob[4]  = e1.x; ob[5]  = e1.y; ob[6]  = e1.z; ob[7]  = e1.w;
        ob[8]  = e2.x; ob[9]  = e2.y; ob[10] = e2.z; ob[11] = e2.w;
        ob[12] = e3.x; ob[13] = e3.y; ob[14] = e3.z; ob[15] = e3.w;

        if (seg == 0) dacc += __builtin_bit_cast(float, mbits & 0xFFFFFE00u);
    }

    // ---- loss partial: sum_threads( xx + 2*dacc ) ----
    float t = fmaf(2.f, dacc, xx);
    #pragma unroll
    for (int m = 32; m; m >>= 1) t += __shfl_down(t, m, 64);
    if (lane == 0) red[wid] = t;
    __syncthreads();
    if (tid == 0) {
        float* part = (float*)(ws + WS_PART);
        part[bid] = red[0] + red[1] + red[2] + red[3];
    }
}

// ---------------- Kernel 3: deterministic final reduce (1 block) ----------------
__global__ __launch_bounds__(256)
void vq_loss(const float* __restrict__ partials, float* __restrict__ out) {
    __shared__ float red[4];
    const int tid = threadIdx.x;
    float acc = partials[tid] + partials[tid + 256];
    #pragma unroll
    for (int m = 32; m; m >>= 1) acc += __shfl_down(acc, m, 64);
    if ((tid & 63) == 0) red[tid >> 6] = acc;
    __syncthreads();
    // loss = 0.25*e_loss + q_loss = 1.25 * mse (forward)
    if (tid == 0) out[0] = 1.25f * (red[0] + red[1] + red[2] + red[3]) / 4194304.0f;
}

extern "C" void kernel_launch(void* const* d_in, const int* in_sizes, int n_in,
                              void* d_out, int out_size, void* d_ws, size_t ws_size,
                              hipStream_t stream) {
    const float* flat = (const float*)d_in[0];   // [65536,64]
    const float* emb  = (const float*)d_in[1];   // [512,64]
    float* out = (float*)d_out;
    char* ws = (char*)d_ws;

    vq_setup<<<16, 256, 0, stream>>>(emb, ws);
    vq_main<<<512, 256, 0, stream>>>(flat, emb, ws, out);
    vq_loss<<<1, 256, 0, stream>>>((const float*)(ws + WS_PART), out);
}

// Round 17
// 23.123 us; speedup vs baseline: 1.3042x; 1.0079x over previous
//
#include <hip/hip_runtime.h>
#include <hip/hip_bf16.h>
#include <cstdint>

// VQ-VAE vector quantize: N=65536 vectors, D=64, K=512 codes.
// d_in[0]: inputs fp32 [65536,64], d_in[1]: embeddings fp32 [512,64]
// d_out: [0]=loss, [1..4194304]=latent (gathered fp32 embeddings)
//
// R17: R16's winning gradient, one more doubling. 256 blocks x 256 threads,
// 4 iters of 64 rows (256 rows/block). Wave keeps its 128-code B-slice in
// VGPRs (one load, amortized 4x); iter i+1 A-loads issued under iter i's
// compute; albuf/cmb rotate (WAR-safe across the per-iter barrier).

typedef __attribute__((ext_vector_type(8))) short bf16x8;
typedef __attribute__((ext_vector_type(4))) float f32x4;

#define NITER 4

__device__ __forceinline__ short f2bf(float f) {
    uint32_t u = __builtin_bit_cast(uint32_t, f);
    u += 0x7FFFu + ((u >> 16) & 1u);   // round-to-nearest-even
    return (short)(u >> 16);
}

__device__ __forceinline__ float sumsq4(float4 v, float acc) {
    return fmaf(v.x, v.x, fmaf(v.y, v.y, fmaf(v.z, v.z, fmaf(v.w, v.w, acc))));
}

__device__ __forceinline__ bf16x8 packpos(float4 a, float4 b) {
    bf16x8 f;
    f[0] = f2bf(a.x); f[1] = f2bf(a.y); f[2] = f2bf(a.z); f[3] = f2bf(a.w);
    f[4] = f2bf(b.x); f[5] = f2bf(b.y); f[6] = f2bf(b.z); f[7] = f2bf(b.w);
    return f;
}

// ws layout (bytes):
//  [0, 65536)     : B fragments bf16(-e), [ct(32)][ks(2)][lane(64)] x 16B
//  [65536, 67584) : ee_t[512] fp32 = 0.5*||e_k||^2, TRANSPOSED [cb(16)][ct(32)]
//  [67584, 68608) : partials[256] fp32
#define WS_EE   65536
#define WS_PART 67584

// ---------------- Kernel 1: setup (16 blocks x 256) ----------------
__global__ __launch_bounds__(256)
void vq_setup(const float* __restrict__ emb, char* __restrict__ ws) {
    const int tid = threadIdx.x, bid = blockIdx.x;
    bf16x8* bfrag = (bf16x8*)ws;
    float* eet = (float*)(ws + WS_EE);

    const int s = bid * 256 + tid;
    const int ct = s >> 7, ks = (s >> 6) & 1, ln = s & 63;
    const int code = (ct << 4) | (ln & 15);
    const int d0 = ks * 32 + ((ln >> 4) << 3);
    const float* src = emb + code * 64 + d0;
    float4 v0 = *(const float4*)src;
    float4 v1 = *(const float4*)(src + 4);
    bf16x8 b;
    b[0] = f2bf(-v0.x); b[1] = f2bf(-v0.y); b[2] = f2bf(-v0.z); b[3] = f2bf(-v0.w);
    b[4] = f2bf(-v1.x); b[5] = f2bf(-v1.y); b[6] = f2bf(-v1.z); b[7] = f2bf(-v1.w);
    bfrag[s] = b;

    if (tid < 32) {
        const int c = bid * 32 + tid;
        const float4* e4 = (const float4*)(emb + c * 64);
        float acc = 0.f;
        #pragma unroll
        for (int q = 0; q < 16; ++q) {
            float4 v = e4[q];
            acc = fmaf(v.x, v.x, fmaf(v.y, v.y, fmaf(v.z, v.z, fmaf(v.w, v.w, acc))));
        }
        eet[(c & 15) * 32 + (c >> 4)] = 0.5f * acc;   // transposed, pre-halved
    }
}

// ---------------- Kernel 2: main (256 blocks x 256) ----------------
// Block owns 256 rows (4 iters x 64). Wave w holds codes [w*128,(w+1)*128)
// in VGPRs; per iter computes partial argmin for 64 rows; LDS combine.
__global__ __launch_bounds__(256)
void vq_main(const float* __restrict__ flat, const float* __restrict__ emb,
             char* __restrict__ ws, float* __restrict__ out) {
    __shared__ bf16x8 albuf[2][4][2][64];   // 8 KB  [buf][rt][ks][lane]
    __shared__ float  cmb[2][4][64];        // 2 KB  [buf][wave][row]
    __shared__ float  red[4];

    const int tid = threadIdx.x, bid = blockIdx.x;
    const int lane = tid & 63, wid = tid >> 6;
    const int cb = lane & 15, g = lane >> 4;
    const int rb = bid * 256;            // block's 256 rows
    const char* wsg = (const char*)ws;

    // ---- A iter-0 loads: wave's own 16 rows ----
    const float* a0src = flat + (long)(rb + wid * 16 + cb) * 64 + (g << 3);
    float4 ar00 = *(const float4*)a0src;
    float4 ar01 = *(const float4*)(a0src + 4);
    float4 ar10 = *(const float4*)(a0src + 32);
    float4 ar11 = *(const float4*)(a0src + 36);

    // ---- B slice: wave's 8 col-tiles -> 64 VGPRs, loaded once ----
    const bf16x8* wsb = (const bf16x8*)wsg;
    bf16x8 bv[8][2];
    #pragma unroll
    for (int c = 0; c < 8; ++c) {
        bv[c][0] = wsb[(wid * 8 + c) * 128 + lane];
        bv[c][1] = wsb[(wid * 8 + c) * 128 + 64 + lane];
    }

    // ---- half-norms for this wave's 8 col-tiles, this lane's col class ----
    float hvv[8];
    {
        const float4* hp = (const float4*)(wsg + WS_EE + cb * 128 + wid * 32);
        float4 h0 = hp[0], h1 = hp[1];
        hvv[0] = h0.x; hvv[1] = h0.y; hvv[2] = h0.z; hvv[3] = h0.w;
        hvv[4] = h1.x; hvv[5] = h1.y; hvv[6] = h1.z; hvv[7] = h1.w;
    }

    // ---- iter-0: ||x||^2 + convert + stage albuf[0] ----
    float xx = 0.f;
    xx = sumsq4(ar00, xx); xx = sumsq4(ar01, xx);
    xx = sumsq4(ar10, xx); xx = sumsq4(ar11, xx);
    albuf[0][wid][0][lane] = packpos(ar00, ar01);
    albuf[0][wid][1][lane] = packpos(ar10, ar11);
    __syncthreads();

    float dacc = 0.f;   // sum of winning dist' for my epilogue rows

    #pragma unroll
    for (int it = 0; it < NITER; ++it) {
        // prefetch iter it+1 A while computing iter it (s_waitcnt deferred
        // to first use after the MFMA block)
        float4 br00, br01, br10, br11;
        if (it < NITER - 1) {
            const float* asrc = flat + (long)(rb + (it + 1) * 64 + wid * 16 + cb) * 64 + (g << 3);
            br00 = *(const float4*)asrc;
            br01 = *(const float4*)(asrc + 4);
            br10 = *(const float4*)(asrc + 32);
            br11 = *(const float4*)(asrc + 36);
        }

        // ---- compute: 4 row-tiles x 8 col-tiles, B from VGPRs ----
        float pm[4][4];
        #pragma unroll
        for (int rt = 0; rt < 4; ++rt)
            #pragma unroll
            for (int j = 0; j < 4; ++j) pm[rt][j] = __builtin_bit_cast(float, 0x7F800000u);

        #pragma unroll
        for (int rt = 0; rt < 4; ++rt) {
            bf16x8 a0 = albuf[it & 1][rt][0][lane];
            bf16x8 a1 = albuf[it & 1][rt][1][lane];
            #pragma unroll
            for (int c = 0; c < 8; ++c) {
                const float h = hvv[c];
                const int colv = ((wid * 8 + c) << 4) | cb;
                f32x4 acc = {h, h, h, h};    // 0.5||e||^2 - x.e   (B = -e)
                acc = __builtin_amdgcn_mfma_f32_16x16x32_bf16(a0, bv[c][0], acc, 0, 0, 0);
                acc = __builtin_amdgcn_mfma_f32_16x16x32_bf16(a1, bv[c][1], acc, 0, 0, 0);
                #pragma unroll
                for (int j = 0; j < 4; ++j) {
                    uint32_t dp = (__builtin_bit_cast(uint32_t, acc[j]) & 0xFFFFFE00u) | (uint32_t)colv;
                    pm[rt][j] = fminf(pm[rt][j], __builtin_bit_cast(float, dp));
                }
            }
        }

        // ---- butterfly min over the 16 column-class lanes ----
        #pragma unroll
        for (int m = 1; m < 16; m <<= 1) {
            #pragma unroll
            for (int rt = 0; rt < 4; ++rt)
                #pragma unroll
                for (int j = 0; j < 4; ++j)
                    pm[rt][j] = fminf(pm[rt][j], __shfl_xor(pm[rt][j], m, 64));
        }
        if (cb == 0) {
            #pragma unroll
            for (int rt = 0; rt < 4; ++rt)
                #pragma unroll
                for (int j = 0; j < 4; ++j)
                    cmb[it & 1][wid][rt * 16 + g * 4 + j] = pm[rt][j];
        }

        // ---- stage iter it+1 A fragments (buffer (it+1)&1 is WAR-safe:
        //      its last readers finished before the PREVIOUS barrier) ----
        if (it < NITER - 1) {
            xx = sumsq4(br00, xx); xx = sumsq4(br01, xx);
            xx = sumsq4(br10, xx); xx = sumsq4(br11, xx);
            albuf[(it + 1) & 1][wid][0][lane] = packpos(br00, br01);
            albuf[(it + 1) & 1][wid][1][lane] = packpos(br10, br11);
        }
        __syncthreads();   // cmb[it&1] + albuf[(it+1)&1] visible to all waves

        // ---- epilogue for this iter's 64 rows ----
        const int row = tid >> 2, seg = tid & 3;
        const float mn = fminf(fminf(cmb[it & 1][0][row], cmb[it & 1][1][row]),
                               fminf(cmb[it & 1][2][row], cmb[it & 1][3][row]));
        const uint32_t mbits = __builtin_bit_cast(uint32_t, mn);
        const int ix = (int)(mbits & 0x1FFu);

        const float4* esrc = (const float4*)(emb + ix * 64 + seg * 16);
        float4 e0 = esrc[0], e1 = esrc[1], e2 = esrc[2], e3 = esrc[3];
        float* ob = out + 1 + (long)(rb + it * 64 + row) * 64 + seg * 16;
        ob[0]  = e0.x; ob[1]  = e0.y; ob[2]  = e0.z; ob[3]  = e0.w;
        ob[4]  = e1.x; ob[5]  = e1.y; ob[6]  = e1.z; ob[7]  = e1.w;
        ob[8]  = e2.x; ob[9]  = e2.y; ob[10] = e2.z; ob[11] = e2.w;
        ob[12] = e3.x; ob[13] = e3.y; ob[14] = e3.z; ob[15] = e3.w;

        if (seg == 0) dacc += __builtin_bit_cast(float, mbits & 0xFFFFFE00u);
    }

    // ---- loss partial: sum_threads( xx + 2*dacc ) ----
    float t = fmaf(2.f, dacc, xx);
    #pragma unroll
    for (int m = 32; m; m >>= 1) t += __shfl_down(t, m, 64);
    if (lane == 0) red[wid] = t;
    __syncthreads();
    if (tid == 0) {
        float* part = (float*)(ws + WS_PART);
        part[bid] = red[0] + red[1] + red[2] + red[3];
    }
}

// ---------------- Kernel 3: deterministic final reduce (1 block) ----------------
__global__ __launch_bounds__(256)
void vq_loss(const float* __restrict__ partials, float* __restrict__ out) {
    __shared__ float red[4];
    const int tid = threadIdx.x;
    float acc = partials[tid];
    #pragma unroll
    for (int m = 32; m; m >>= 1) acc += __shfl_down(acc, m, 64);
    if ((tid & 63) == 0) red[tid >> 6] = acc;
    __syncthreads();
    // loss = 0.25*e_loss + q_loss = 1.25 * mse (forward)
    if (tid == 0) out[0] = 1.25f * (red[0] + red[1] + red[2] + red[3]) / 4194304.0f;
}

extern "C" void kernel_launch(void* const* d_in, const int* in_sizes, int n_in,
                              void* d_out, int out_size, void* d_ws, size_t ws_size,
                              hipStream_t stream) {
    const float* flat = (const float*)d_in[0];   // [65536,64]
    const float* emb  = (const float*)d_in[1];   // [512,64]
    float* out = (float*)d_out;
    char* ws = (char*)d_ws;

    vq_setup<<<16, 256, 0, stream>>>(emb, ws);
    vq_main<<<256, 256, 0, stream>>>(flat, emb, ws, out);
    vq_loss<<<1, 256, 0, stream>>>((const float*)(ws + WS_PART), out);
}

// Round 18
// 21.039 us; speedup vs baseline: 1.4334x; 1.0990x over previous
//
#include <hip/hip_runtime.h>
#include <hip/hip_bf16.h>
#include <cstdint>

// VQ-VAE vector quantize: N=65536 vectors, D=64, K=512 codes.
// d_in[0]: inputs fp32 [65536,64], d_in[1]: embeddings fp32 [512,64]
// d_out: [0]=loss, [1..4194304]=latent (gathered fp32 embeddings)
//
// R18: amortization (R17) + TLP (R16) composed. 256 blocks x 512 threads
// (8 waves = 2/SIMD), 256 rows/block in 4 iters of 64. Wave w owns a
// 64-code slice (4 col-tiles, 32 VGPRs); A staged 8-way (slot rt=w>>1,
// ks=w&1); 8-way cmb combine; prefetch + rotating buffers as R17.

typedef __attribute__((ext_vector_type(8))) short bf16x8;
typedef __attribute__((ext_vector_type(4))) float f32x4;

#define NITER 4

__device__ __forceinline__ short f2bf(float f) {
    uint32_t u = __builtin_bit_cast(uint32_t, f);
    u += 0x7FFFu + ((u >> 16) & 1u);   // round-to-nearest-even
    return (short)(u >> 16);
}

__device__ __forceinline__ float sumsq4(float4 v, float acc) {
    return fmaf(v.x, v.x, fmaf(v.y, v.y, fmaf(v.z, v.z, fmaf(v.w, v.w, acc))));
}

__device__ __forceinline__ bf16x8 packpos(float4 a, float4 b) {
    bf16x8 f;
    f[0] = f2bf(a.x); f[1] = f2bf(a.y); f[2] = f2bf(a.z); f[3] = f2bf(a.w);
    f[4] = f2bf(b.x); f[5] = f2bf(b.y); f[6] = f2bf(b.z); f[7] = f2bf(b.w);
    return f;
}

// ws layout (bytes):
//  [0, 65536)     : B fragments bf16(-e), [ct(32)][ks(2)][lane(64)] x 16B
//  [65536, 67584) : ee_t[512] fp32 = 0.5*||e_k||^2, TRANSPOSED [cb(16)][ct(32)]
//  [67584, 68608) : partials[256] fp32
#define WS_EE   65536
#define WS_PART 67584

// ---------------- Kernel 1: setup (16 blocks x 256) ----------------
__global__ __launch_bounds__(256)
void vq_setup(const float* __restrict__ emb, char* __restrict__ ws) {
    const int tid = threadIdx.x, bid = blockIdx.x;
    bf16x8* bfrag = (bf16x8*)ws;
    float* eet = (float*)(ws + WS_EE);

    const int s = bid * 256 + tid;
    const int ct = s >> 7, ks = (s >> 6) & 1, ln = s & 63;
    const int code = (ct << 4) | (ln & 15);
    const int d0 = ks * 32 + ((ln >> 4) << 3);
    const float* src = emb + code * 64 + d0;
    float4 v0 = *(const float4*)src;
    float4 v1 = *(const float4*)(src + 4);
    bf16x8 b;
    b[0] = f2bf(-v0.x); b[1] = f2bf(-v0.y); b[2] = f2bf(-v0.z); b[3] = f2bf(-v0.w);
    b[4] = f2bf(-v1.x); b[5] = f2bf(-v1.y); b[6] = f2bf(-v1.z); b[7] = f2bf(-v1.w);
    bfrag[s] = b;

    if (tid < 32) {
        const int c = bid * 32 + tid;
        const float4* e4 = (const float4*)(emb + c * 64);
        float acc = 0.f;
        #pragma unroll
        for (int q = 0; q < 16; ++q) {
            float4 v = e4[q];
            acc = fmaf(v.x, v.x, fmaf(v.y, v.y, fmaf(v.z, v.z, fmaf(v.w, v.w, acc))));
        }
        eet[(c & 15) * 32 + (c >> 4)] = 0.5f * acc;   // transposed, pre-halved
    }
}

// ---------------- Kernel 2: main (256 blocks x 512) ----------------
// Block owns 256 rows (4 iters x 64). Wave w holds codes [w*64,(w+1)*64)
// in 32 VGPRs; stages A slot (rt=w>>1, ks=w&1); 8-way LDS combine.
__global__ __launch_bounds__(512)
void vq_main(const float* __restrict__ flat, const float* __restrict__ emb,
             char* __restrict__ ws, float* __restrict__ out) {
    __shared__ bf16x8 albuf[2][4][2][64];   // 16 KB [buf][rt][ks][lane]
    __shared__ float  cmb[2][8][64];        // 4 KB  [buf][wave][row]
    __shared__ float  red[8];

    const int tid = threadIdx.x, bid = blockIdx.x;
    const int lane = tid & 63, wid = tid >> 6;      // 8 waves
    const int cb = lane & 15, g = lane >> 4;
    const int rb = bid * 256;                       // block's 256 rows
    const int srt = wid >> 1, sks = wid & 1;        // this wave's staging slot
    const char* wsg = (const char*)ws;

    // ---- A iter-0 loads: wave's staging slot (16 rows x 32 dims) ----
    const float* a0src = flat + (long)(rb + srt * 16 + cb) * 64 + sks * 32 + (g << 3);
    float4 ar0 = *(const float4*)a0src;
    float4 ar1 = *(const float4*)(a0src + 4);

    // ---- B slice: wave's 4 col-tiles -> 32 VGPRs, loaded once ----
    const bf16x8* wsb = (const bf16x8*)wsg;
    bf16x8 bv[4][2];
    #pragma unroll
    for (int c = 0; c < 4; ++c) {
        bv[c][0] = wsb[(wid * 4 + c) * 128 + lane];
        bv[c][1] = wsb[(wid * 4 + c) * 128 + 64 + lane];
    }

    // ---- half-norms for this wave's 4 col-tiles, this lane's col class ----
    float hvv[4];
    {
        float4 h = *(const float4*)(wsg + WS_EE + cb * 128 + wid * 16);
        hvv[0] = h.x; hvv[1] = h.y; hvv[2] = h.z; hvv[3] = h.w;
    }

    // ---- iter-0: ||x||^2 partial + convert + stage albuf[0] ----
    float xx = 0.f;
    xx = sumsq4(ar0, xx); xx = sumsq4(ar1, xx);
    albuf[0][srt][sks][lane] = packpos(ar0, ar1);
    __syncthreads();

    float dacc = 0.f;   // sum of winning dist' for my epilogue rows

    #pragma unroll
    for (int it = 0; it < NITER; ++it) {
        // prefetch next iter's staging slot under this iter's compute
        float4 br0, br1;
        if (it < NITER - 1) {
            const float* asrc = flat + (long)(rb + (it + 1) * 64 + srt * 16 + cb) * 64
                                + sks * 32 + (g << 3);
            br0 = *(const float4*)asrc;
            br1 = *(const float4*)(asrc + 4);
        }

        // ---- compute: 4 row-tiles x 4 code-tiles, B from VGPRs ----
        float pm[4][4];
        #pragma unroll
        for (int rt = 0; rt < 4; ++rt)
            #pragma unroll
            for (int j = 0; j < 4; ++j) pm[rt][j] = __builtin_bit_cast(float, 0x7F800000u);

        #pragma unroll
        for (int rt = 0; rt < 4; ++rt) {
            bf16x8 a0 = albuf[it & 1][rt][0][lane];
            bf16x8 a1 = albuf[it & 1][rt][1][lane];
            #pragma unroll
            for (int c = 0; c < 4; ++c) {
                const float h = hvv[c];
                const int colv = ((wid * 4 + c) << 4) | cb;
                f32x4 acc = {h, h, h, h};    // 0.5||e||^2 - x.e   (B = -e)
                acc = __builtin_amdgcn_mfma_f32_16x16x32_bf16(a0, bv[c][0], acc, 0, 0, 0);
                acc = __builtin_amdgcn_mfma_f32_16x16x32_bf16(a1, bv[c][1], acc, 0, 0, 0);
                #pragma unroll
                for (int j = 0; j < 4; ++j) {
                    uint32_t dp = (__builtin_bit_cast(uint32_t, acc[j]) & 0xFFFFFE00u) | (uint32_t)colv;
                    pm[rt][j] = fminf(pm[rt][j], __builtin_bit_cast(float, dp));
                }
            }
        }

        // ---- butterfly min over the 16 column-class lanes ----
        #pragma unroll
        for (int m = 1; m < 16; m <<= 1) {
            #pragma unroll
            for (int rt = 0; rt < 4; ++rt)
                #pragma unroll
                for (int j = 0; j < 4; ++j)
                    pm[rt][j] = fminf(pm[rt][j], __shfl_xor(pm[rt][j], m, 64));
        }
        if (cb == 0) {
            #pragma unroll
            for (int rt = 0; rt < 4; ++rt)
                #pragma unroll
                for (int j = 0; j < 4; ++j)
                    cmb[it & 1][wid][rt * 16 + g * 4 + j] = pm[rt][j];
        }

        // ---- stage next iter's A (rotating buffer, WAR-safe) ----
        if (it < NITER - 1) {
            xx = sumsq4(br0, xx); xx = sumsq4(br1, xx);
            albuf[(it + 1) & 1][srt][sks][lane] = packpos(br0, br1);
        }
        __syncthreads();   // cmb[it&1] + albuf[(it+1)&1] visible

        // ---- epilogue: row = tid>>3 (0..63), seg = tid&7 (8 floats) ----
        const int row = tid >> 3, seg = tid & 7;
        float mn = cmb[it & 1][0][row];
        #pragma unroll
        for (int w = 1; w < 8; ++w) mn = fminf(mn, cmb[it & 1][w][row]);
        const uint32_t mbits = __builtin_bit_cast(uint32_t, mn);
        const int ix = (int)(mbits & 0x1FFu);

        const float4* esrc = (const float4*)(emb + ix * 64 + seg * 8);
        float4 e0 = esrc[0], e1 = esrc[1];
        float* ob = out + 1 + (long)(rb + it * 64 + row) * 64 + seg * 8;
        ob[0] = e0.x; ob[1] = e0.y; ob[2] = e0.z; ob[3] = e0.w;
        ob[4] = e1.x; ob[5] = e1.y; ob[6] = e1.z; ob[7] = e1.w;

        if (seg == 0) dacc += __builtin_bit_cast(float, mbits & 0xFFFFFE00u);
    }

    // ---- loss partial: sum_threads( xx + 2*dacc ) ----
    float t = fmaf(2.f, dacc, xx);
    #pragma unroll
    for (int m = 32; m; m >>= 1) t += __shfl_down(t, m, 64);
    if (lane == 0) red[wid] = t;
    __syncthreads();
    if (tid == 0) {
        float s = 0.f;
        #pragma unroll
        for (int i = 0; i < 8; ++i) s += red[i];
        ((float*)(ws + WS_PART))[bid] = s;
    }
}

// ---------------- Kernel 3: deterministic final reduce (1 block) ----------------
__global__ __launch_bounds__(256)
void vq_loss(const float* __restrict__ partials, float* __restrict__ out) {
    __shared__ float red[4];
    const int tid = threadIdx.x;
    float acc = partials[tid];
    #pragma unroll
    for (int m = 32; m; m >>= 1) acc += __shfl_down(acc, m, 64);
    if ((tid & 63) == 0) red[tid >> 6] = acc;
    __syncthreads();
    // loss = 0.25*e_loss + q_loss = 1.25 * mse (forward)
    if (tid == 0) out[0] = 1.25f * (red[0] + red[1] + red[2] + red[3]) / 4194304.0f;
}

extern "C" void kernel_launch(void* const* d_in, const int* in_sizes, int n_in,
                              void* d_out, int out_size, void* d_ws, size_t ws_size,
                              hipStream_t stream) {
    const float* flat = (const float*)d_in[0];   // [65536,64]
    const float* emb  = (const float*)d_in[1];   // [512,64]
    float* out = (float*)d_out;
    char* ws = (char*)d_ws;

    vq_setup<<<16, 256, 0, stream>>>(emb, ws);
    vq_main<<<256, 512, 0, stream>>>(flat, emb, ws, out);
    vq_loss<<<1, 256, 0, stream>>>((const float*)(ws + WS_PART), out);
}